// Round 6
// baseline (50.356 us; speedup 1.0000x reference)
//
#include <hip/hip_runtime.h>

#define IN_DIM  4096
#define OUT_DIM 8192
#define BATCH   4096
#define ROWS    4          // rows staged per block, interleaved per-column (b128 gather)
#define TPB     512
#define CPT     4          // columns per thread per chunk
#define NCHUNK  (OUT_DIM / (TPB * CPT))   // 4
#define CSTRIDE (TPB * CPT)               // 2048 columns per chunk

typedef float f32x4 __attribute__((ext_vector_type(4)));

// swizzled LDS byte address of the 4-row group for column c (bijective involution
// within the 64 KB tile); applied on BOTH the staging write and the gather read.
__device__ __forceinline__ uint32_t swz(uint32_t c) {
    return (c ^ ((c >> 3) & 7u)) << 4;   // max 65520 -> fits u16
}

// difflogic op-coefficient table: op_i(a,b) = T[i][0] + T[i][1]*a + T[i][2]*b + T[i][3]*ab
__device__ __constant__ float c_T[16][4] = {
    {0.f,  0.f,  0.f,  0.f},
    {0.f,  0.f,  0.f,  1.f},
    {0.f,  1.f,  0.f, -1.f},
    {0.f,  1.f,  0.f,  0.f},
    {0.f,  0.f,  1.f, -1.f},
    {0.f,  0.f,  1.f,  0.f},
    {0.f,  1.f,  1.f, -2.f},
    {0.f,  1.f,  1.f, -1.f},
    {1.f, -1.f, -1.f,  1.f},
    {1.f, -1.f, -1.f,  2.f},
    {1.f,  0.f, -1.f,  0.f},
    {1.f,  0.f, -1.f,  1.f},
    {1.f, -1.f,  0.f,  0.f},
    {1.f, -1.f,  0.f,  1.f},
    {1.f,  0.f,  0.f, -1.f},
    {1.f,  0.f,  0.f,  0.f},
};

// Per column j: coeff[j] = softmax(weight[j,:]) @ T, and spk[j] = packed
// pre-swizzled LDS byte offsets of the two gather operands (u16|u16).
__global__ __launch_bounds__(256) void prep_kernel(const float* __restrict__ w,
                                                   const int* __restrict__ idx,
                                                   float4* __restrict__ coeff,
                                                   uint32_t* __restrict__ spk) {
    int j = blockIdx.x * blockDim.x + threadIdx.x;
    if (j >= OUT_DIM) return;
    const float4* wp = (const float4*)(w + (size_t)j * 16);
    float4 a0 = wp[0], a1 = wp[1], a2 = wp[2], a3 = wp[3];
    float v[16] = {a0.x, a0.y, a0.z, a0.w, a1.x, a1.y, a1.z, a1.w,
                   a2.x, a2.y, a2.z, a2.w, a3.x, a3.y, a3.z, a3.w};
    float m = v[0];
#pragma unroll
    for (int i = 1; i < 16; ++i) m = fmaxf(m, v[i]);
    float s = 0.f, c0 = 0.f, c1 = 0.f, c2 = 0.f, c3 = 0.f;
#pragma unroll
    for (int i = 0; i < 16; ++i) {
        float e = __expf(v[i] - m);
        s += e;
        c0 += e * c_T[i][0];
        c1 += e * c_T[i][1];
        c2 += e * c_T[i][2];
        c3 += e * c_T[i][3];
    }
    float inv = 1.f / s;
    coeff[j] = make_float4(c0 * inv, c1 * inv, c2 * inv, c3 * inv);
    spk[j] = swz((uint32_t)idx[j]) | (swz((uint32_t)idx[OUT_DIM + j]) << 16);
}

__device__ __forceinline__ void gather8(const char* lds, uint4 P,
                                        f32x4& A0, f32x4& B0, f32x4& A1, f32x4& B1,
                                        f32x4& A2, f32x4& B2, f32x4& A3, f32x4& B3) {
    A0 = *(const f32x4*)(lds + (P.x & 0xFFFFu));
    B0 = *(const f32x4*)(lds + (P.x >> 16));
    A1 = *(const f32x4*)(lds + (P.y & 0xFFFFu));
    B1 = *(const f32x4*)(lds + (P.y >> 16));
    A2 = *(const f32x4*)(lds + (P.z & 0xFFFFu));
    B2 = *(const f32x4*)(lds + (P.z >> 16));
    A3 = *(const f32x4*)(lds + (P.w & 0xFFFFu));
    B3 = *(const f32x4*)(lds + (P.w >> 16));
}

#define POLY(C, a, b) ((C).x + (C).y * (a) + (C).z * (b) + (C).w * ((a) * (b)))

__device__ __forceinline__ void compute_store(float* __restrict__ out, int row0, int j,
                                              float4 C0, float4 C1, float4 C2, float4 C3,
                                              f32x4 A0, f32x4 B0, f32x4 A1, f32x4 B1,
                                              f32x4 A2, f32x4 B2, f32x4 A3, f32x4 B3) {
    f32x4 o0, o1, o2, o3;  // o[r] holds cols j..j+3 for row r
    o0.x = POLY(C0, A0.x, B0.x); o1.x = POLY(C0, A0.y, B0.y);
    o2.x = POLY(C0, A0.z, B0.z); o3.x = POLY(C0, A0.w, B0.w);
    o0.y = POLY(C1, A1.x, B1.x); o1.y = POLY(C1, A1.y, B1.y);
    o2.y = POLY(C1, A1.z, B1.z); o3.y = POLY(C1, A1.w, B1.w);
    o0.z = POLY(C2, A2.x, B2.x); o1.z = POLY(C2, A2.y, B2.y);
    o2.z = POLY(C2, A2.z, B2.z); o3.z = POLY(C2, A2.w, B2.w);
    o0.w = POLY(C3, A3.x, B3.x); o1.w = POLY(C3, A3.y, B3.y);
    o2.w = POLY(C3, A3.z, B3.z); o3.w = POLY(C3, A3.w, B3.w);
    __builtin_nontemporal_store(o0, (f32x4*)(out + (size_t)(row0 + 0) * OUT_DIM + j));
    __builtin_nontemporal_store(o1, (f32x4*)(out + (size_t)(row0 + 1) * OUT_DIM + j));
    __builtin_nontemporal_store(o2, (f32x4*)(out + (size_t)(row0 + 2) * OUT_DIM + j));
    __builtin_nontemporal_store(o3, (f32x4*)(out + (size_t)(row0 + 3) * OUT_DIM + j));
}

// 4 rows staged in LDS as swizzled per-column 16 B groups; one ds_read_b128
// serves 4 rows. Gathers are software-pipelined ONE CHUNK AHEAD (metadata two
// ahead), so compute waits only on reads issued a full chunk earlier.
__global__ __launch_bounds__(TPB) void logic_main(const float* __restrict__ x,
                                                  const uint32_t* __restrict__ spk,
                                                  const float4* __restrict__ coeff,
                                                  float* __restrict__ out) {
    __shared__ float xs[ROWS * IN_DIM];  // 64 KB
    const char* lds = (const char*)xs;

    const int row0 = blockIdx.x * ROWS;
    const int jbase = threadIdx.x * CPT;

    // metadata prefetch: chunks 0 and 1 (overlaps with staging)
    uint4 P0 = *(const uint4*)(spk + jbase);
    uint4 P1 = *(const uint4*)(spk + jbase + CSTRIDE);
    float4 C00 = coeff[jbase + 0], C01 = coeff[jbase + 1];
    float4 C02 = coeff[jbase + 2], C03 = coeff[jbase + 3];

    // --- stage 4 rows, transposing to interleaved+swizzled layout ---
    {
        const f32x4* rp = (const f32x4*)(x + (size_t)row0 * IN_DIM);
#pragma unroll
        for (int it = 0; it < IN_DIM / 4 / TPB; ++it) {  // 2 iters
            const int t = it * TPB + threadIdx.x;        // col-group (4 cols)
            f32x4 r0 = __builtin_nontemporal_load(rp + t);
            f32x4 r1 = __builtin_nontemporal_load(rp + t + IN_DIM / 4);
            f32x4 r2 = __builtin_nontemporal_load(rp + t + 2 * IN_DIM / 4);
            f32x4 r3 = __builtin_nontemporal_load(rp + t + 3 * IN_DIM / 4);
#pragma unroll
            for (int k = 0; k < 4; ++k) {
                f32x4 v; v.x = r0[k]; v.y = r1[k]; v.z = r2[k]; v.w = r3[k];
                *(f32x4*)((char*)xs + swz(4u * t + k)) = v;
            }
        }
    }
    __syncthreads();

    f32x4 a0, b0, a1, b1, a2, b2, a3, b3;          // chunk k gathers
    f32x4 n0, m0, n1, m1, n2, m2, n3, m3;          // chunk k+1 gathers

    gather8(lds, P0, a0, b0, a1, b1, a2, b2, a3, b3);   // issue chunk 0

    // ---- chunk 0 ----
    uint4 P2 = *(const uint4*)(spk + jbase + 2 * CSTRIDE);
    gather8(lds, P1, n0, m0, n1, m1, n2, m2, n3, m3);   // issue chunk 1
    float4 C10 = coeff[jbase + CSTRIDE + 0], C11 = coeff[jbase + CSTRIDE + 1];
    float4 C12 = coeff[jbase + CSTRIDE + 2], C13 = coeff[jbase + CSTRIDE + 3];
    compute_store(out, row0, jbase, C00, C01, C02, C03,
                  a0, b0, a1, b1, a2, b2, a3, b3);

    // ---- chunk 1 ----
    uint4 P3 = *(const uint4*)(spk + jbase + 3 * CSTRIDE);
    gather8(lds, P2, a0, b0, a1, b1, a2, b2, a3, b3);   // issue chunk 2
    float4 C20 = coeff[jbase + 2 * CSTRIDE + 0], C21 = coeff[jbase + 2 * CSTRIDE + 1];
    float4 C22 = coeff[jbase + 2 * CSTRIDE + 2], C23 = coeff[jbase + 2 * CSTRIDE + 3];
    compute_store(out, row0, jbase + CSTRIDE, C10, C11, C12, C13,
                  n0, m0, n1, m1, n2, m2, n3, m3);

    // ---- chunk 2 ----
    gather8(lds, P3, n0, m0, n1, m1, n2, m2, n3, m3);   // issue chunk 3
    float4 C30 = coeff[jbase + 3 * CSTRIDE + 0], C31 = coeff[jbase + 3 * CSTRIDE + 1];
    float4 C32 = coeff[jbase + 3 * CSTRIDE + 2], C33 = coeff[jbase + 3 * CSTRIDE + 3];
    compute_store(out, row0, jbase + 2 * CSTRIDE, C20, C21, C22, C23,
                  a0, b0, a1, b1, a2, b2, a3, b3);

    // ---- chunk 3 ----
    compute_store(out, row0, jbase + 3 * CSTRIDE, C30, C31, C32, C33,
                  n0, m0, n1, m1, n2, m2, n3, m3);
}

extern "C" void kernel_launch(void* const* d_in, const int* in_sizes, int n_in,
                              void* d_out, int out_size, void* d_ws, size_t ws_size,
                              hipStream_t stream) {
    const float* x   = (const float*)d_in[0];
    const int*   idx = (const int*)d_in[1];     // (2, OUT_DIM) int32
    const float* w   = (const float*)d_in[2];   // (OUT_DIM, 16)
    float* out = (float*)d_out;
    float4*   coeff = (float4*)d_ws;                        // 128 KB
    uint32_t* spk   = (uint32_t*)((char*)d_ws + OUT_DIM * sizeof(float4));  // 32 KB

    prep_kernel<<<OUT_DIM / 256, 256, 0, stream>>>(w, idx, coeff, spk);
    logic_main<<<BATCH / ROWS, TPB, 0, stream>>>(x, spk, coeff, out);
}

// Round 7
// 39.765 us; speedup vs baseline: 1.2663x; 1.2663x over previous
//
#include <hip/hip_runtime.h>

#define IN_DIM  4096
#define OUT_DIM 8192
#define BATCH   4096
#define ROWS    4          // rows staged per block, interleaved per-column (b128 gather)
#define TPB     512
#define CPT     4          // columns per thread per chunk
#define NCHUNK  (OUT_DIM / (TPB * CPT))   // 4
#define CSTRIDE (TPB * CPT)               // 2048 columns per chunk

typedef float f32x4 __attribute__((ext_vector_type(4)));

// swizzled LDS byte address of the 4-row group for column c (bijective involution
// within the 64 KB tile); applied on BOTH the staging write and the gather read.
__device__ __forceinline__ uint32_t swz(uint32_t c) {
    return (c ^ ((c >> 3) & 7u)) << 4;   // max 65520 -> fits u16
}

// difflogic op-coefficient table: op_i(a,b) = T[i][0] + T[i][1]*a + T[i][2]*b + T[i][3]*ab
__device__ __constant__ float c_T[16][4] = {
    {0.f,  0.f,  0.f,  0.f},
    {0.f,  0.f,  0.f,  1.f},
    {0.f,  1.f,  0.f, -1.f},
    {0.f,  1.f,  0.f,  0.f},
    {0.f,  0.f,  1.f, -1.f},
    {0.f,  0.f,  1.f,  0.f},
    {0.f,  1.f,  1.f, -2.f},
    {0.f,  1.f,  1.f, -1.f},
    {1.f, -1.f, -1.f,  1.f},
    {1.f, -1.f, -1.f,  2.f},
    {1.f,  0.f, -1.f,  0.f},
    {1.f,  0.f, -1.f,  1.f},
    {1.f, -1.f,  0.f,  0.f},
    {1.f, -1.f,  0.f,  1.f},
    {1.f,  0.f,  0.f, -1.f},
    {1.f,  0.f,  0.f,  0.f},
};

// Per column j: coeff[j] = softmax(weight[j,:]) @ T, and spk[j] = packed
// pre-swizzled LDS byte offsets of the two gather operands (u16|u16).
__global__ __launch_bounds__(256) void prep_kernel(const float* __restrict__ w,
                                                   const int* __restrict__ idx,
                                                   float4* __restrict__ coeff,
                                                   uint32_t* __restrict__ spk) {
    int j = blockIdx.x * blockDim.x + threadIdx.x;
    if (j >= OUT_DIM) return;
    const float4* wp = (const float4*)(w + (size_t)j * 16);
    float4 a0 = wp[0], a1 = wp[1], a2 = wp[2], a3 = wp[3];
    float v[16] = {a0.x, a0.y, a0.z, a0.w, a1.x, a1.y, a1.z, a1.w,
                   a2.x, a2.y, a2.z, a2.w, a3.x, a3.y, a3.z, a3.w};
    float m = v[0];
#pragma unroll
    for (int i = 1; i < 16; ++i) m = fmaxf(m, v[i]);
    float s = 0.f, c0 = 0.f, c1 = 0.f, c2 = 0.f, c3 = 0.f;
#pragma unroll
    for (int i = 0; i < 16; ++i) {
        float e = __expf(v[i] - m);
        s += e;
        c0 += e * c_T[i][0];
        c1 += e * c_T[i][1];
        c2 += e * c_T[i][2];
        c3 += e * c_T[i][3];
    }
    float inv = 1.f / s;
    coeff[j] = make_float4(c0 * inv, c1 * inv, c2 * inv, c3 * inv);
    spk[j] = swz((uint32_t)idx[j]) | (swz((uint32_t)idx[OUT_DIM + j]) << 16);
}

// R4 skeleton (metadata-only double-buffer prefetch, gathers at top of each
// unrolled chunk, launch_bounds(512,4) clamps VGPR<=128 -> 2 blocks/CU) plus
// precomputed packed swizzled gather offsets from prep_kernel.
__global__ __launch_bounds__(TPB, 4) void logic_main(const float* __restrict__ x,
                                                     const uint32_t* __restrict__ spk,
                                                     const float4* __restrict__ coeff,
                                                     float* __restrict__ out) {
    __shared__ float xs[ROWS * IN_DIM];  // 64 KB, swizzled 4-row column groups
    const char* lds = (const char*)xs;

    const int row0 = blockIdx.x * ROWS;
    const int jbase = threadIdx.x * CPT;

    // --- prefetch chunk 0's metadata (overlaps with staging) ---
    uint4  P = *(const uint4*)(spk + jbase);
    float4 c0 = coeff[jbase + 0];
    float4 c1 = coeff[jbase + 1];
    float4 c2 = coeff[jbase + 2];
    float4 c3 = coeff[jbase + 3];

    // --- stage 4 rows, transposing to interleaved+swizzled layout ---
    {
        const float4* rp = (const float4*)(x + (size_t)row0 * IN_DIM);
#pragma unroll
        for (int it = 0; it < IN_DIM / 4 / TPB; ++it) {  // 2 iters
            const int t = it * TPB + threadIdx.x;        // col-group (4 cols)
            float4 r0 = rp[t];
            float4 r1 = rp[t + IN_DIM / 4];
            float4 r2 = rp[t + 2 * IN_DIM / 4];
            float4 r3 = rp[t + 3 * IN_DIM / 4];
            const float* p0 = &r0.x; const float* p1 = &r1.x;
            const float* p2 = &r2.x; const float* p3 = &r3.x;
#pragma unroll
            for (int k = 0; k < 4; ++k) {
                f32x4 v; v.x = p0[k]; v.y = p1[k]; v.z = p2[k]; v.w = p3[k];
                *(f32x4*)((char*)xs + swz(4u * t + k)) = v;
            }
        }
    }
    __syncthreads();

#pragma unroll
    for (int chunk = 0; chunk < NCHUNK; ++chunk) {
        const int j = chunk * CSTRIDE + jbase;
        const uint4  IP = P;
        const float4 C0 = c0, C1 = c1, C2 = c2, C3 = c3;
        if (chunk < NCHUNK - 1) {
            const int jn = j + CSTRIDE;
            P  = *(const uint4*)(spk + jn);
            c0 = coeff[jn + 0];
            c1 = coeff[jn + 1];
            c2 = coeff[jn + 2];
            c3 = coeff[jn + 3];
        }
        // gathers: one b128 per (col, a/b) serves all 4 rows; offsets pre-swizzled
        const f32x4 A0 = *(const f32x4*)(lds + (IP.x & 0xFFFFu));
        const f32x4 B0 = *(const f32x4*)(lds + (IP.x >> 16));
        const f32x4 A1 = *(const f32x4*)(lds + (IP.y & 0xFFFFu));
        const f32x4 B1 = *(const f32x4*)(lds + (IP.y >> 16));
        const f32x4 A2 = *(const f32x4*)(lds + (IP.z & 0xFFFFu));
        const f32x4 B2 = *(const f32x4*)(lds + (IP.z >> 16));
        const f32x4 A3 = *(const f32x4*)(lds + (IP.w & 0xFFFFu));
        const f32x4 B3 = *(const f32x4*)(lds + (IP.w >> 16));

        f32x4 o0, o1, o2, o3;  // o[r] holds cols j..j+3 for row r
#define POLY(C, a, b) ((C).x + (C).y * (a) + (C).z * (b) + (C).w * ((a) * (b)))
        o0.x = POLY(C0, A0.x, B0.x); o1.x = POLY(C0, A0.y, B0.y);
        o2.x = POLY(C0, A0.z, B0.z); o3.x = POLY(C0, A0.w, B0.w);
        o0.y = POLY(C1, A1.x, B1.x); o1.y = POLY(C1, A1.y, B1.y);
        o2.y = POLY(C1, A1.z, B1.z); o3.y = POLY(C1, A1.w, B1.w);
        o0.z = POLY(C2, A2.x, B2.x); o1.z = POLY(C2, A2.y, B2.y);
        o2.z = POLY(C2, A2.z, B2.z); o3.z = POLY(C2, A2.w, B2.w);
        o0.w = POLY(C3, A3.x, B3.x); o1.w = POLY(C3, A3.y, B3.y);
        o2.w = POLY(C3, A3.z, B3.z); o3.w = POLY(C3, A3.w, B3.w);
#undef POLY

        __builtin_nontemporal_store(o0, (f32x4*)(out + (size_t)(row0 + 0) * OUT_DIM + j));
        __builtin_nontemporal_store(o1, (f32x4*)(out + (size_t)(row0 + 1) * OUT_DIM + j));
        __builtin_nontemporal_store(o2, (f32x4*)(out + (size_t)(row0 + 2) * OUT_DIM + j));
        __builtin_nontemporal_store(o3, (f32x4*)(out + (size_t)(row0 + 3) * OUT_DIM + j));
    }
}

extern "C" void kernel_launch(void* const* d_in, const int* in_sizes, int n_in,
                              void* d_out, int out_size, void* d_ws, size_t ws_size,
                              hipStream_t stream) {
    const float* x   = (const float*)d_in[0];
    const int*   idx = (const int*)d_in[1];     // (2, OUT_DIM) int32
    const float* w   = (const float*)d_in[2];   // (OUT_DIM, 16)
    float* out = (float*)d_out;
    float4*   coeff = (float4*)d_ws;                                        // 128 KB
    uint32_t* spk   = (uint32_t*)((char*)d_ws + OUT_DIM * sizeof(float4));  // 32 KB

    prep_kernel<<<OUT_DIM / 256, 256, 0, stream>>>(w, idx, coeff, spk);
    logic_main<<<BATCH / ROWS, TPB, 0, stream>>>(x, spk, coeff, out);
}